// Round 18
// baseline (134.082 us; speedup 1.0000x reference)
//
#include <hip/hip_runtime.h>
#include <hip/hip_bf16.h>

// ---------- types ----------
typedef __attribute__((ext_vector_type(8))) short short8;      // 8 x bf16 (4 VGPR) MFMA frag
typedef __attribute__((ext_vector_type(4))) float f32x4;       // MFMA accumulator
typedef __attribute__((ext_vector_type(4))) unsigned short u16x4;

// ---------- constants ----------
#define NB 4
#define NN 1024
#define NC 768
#define NH 12
#define TC 2304

// workspace byte offsets
#define OFF_XB   0ul
#define OFF_WQ   6291456ul
#define OFF_WMU  (OFF_WQ + 3538944ul)
#define OFF_WLS  (OFF_WMU + 589824ul)
#define OFF_QKVB (OFF_WLS + 589824ul)
#define OFF_V3   (OFF_QKVB + 18874368ul)
#define OFF_OUTB (OFF_V3 + 6291456ul)

__device__ __forceinline__ unsigned short f2bf(float f) {
    unsigned int u = __float_as_uint(f);
    u = (u + 0x7FFFu + ((u >> 16) & 1u)) >> 16;
    return (unsigned short)u;
}

__device__ __forceinline__ void gload_lds16(const unsigned short* g, unsigned short* l) {
    __builtin_amdgcn_global_load_lds(
        (const __attribute__((address_space(1))) unsigned int*)g,
        (__attribute__((address_space(3))) unsigned int*)l, 16, 0, 0);
}

__device__ __forceinline__ void gload16(short8& dst, const unsigned short* p) {
    asm volatile("global_load_dwordx4 %0, %1, off" : "=v"(dst) : "v"(p));
}
__device__ __forceinline__ void gloadf4(f32x4& dst, const float* p) {
    asm volatile("global_load_dwordx4 %0, %1, off" : "=v"(dst) : "v"(p));
}
#define WAITV(N) do { asm volatile("s_waitcnt vmcnt(" #N ")" ::: "memory"); \
                      __builtin_amdgcn_sched_barrier(0); } while (0)
#define SBAR()   __builtin_amdgcn_sched_barrier(0)

// ---------- fused cast f32 -> bf16 ----------
__global__ void cast_all(const float* __restrict__ x, const float* __restrict__ qkv_w,
                         const float* __restrict__ mu_w, const float* __restrict__ ls_w,
                         unsigned short* __restrict__ dst) {
    int i = blockIdx.x * blockDim.x + threadIdx.x;
    const float* src; int off;
    if (i < 786432)            { src = x;     off = i; }
    else if (i < 1228800)      { src = qkv_w; off = i - 786432; }
    else if (i < 1302528)      { src = mu_w;  off = i - 1228800; }
    else                       { src = ls_w;  off = i - 1302528; }
    f32x4 v = ((const f32x4*)src)[off];
    u16x4 o;
#pragma unroll
    for (int j = 0; j < 4; ++j) o[j] = f2bf(v[j]);
    ((u16x4*)dst)[i] = o;
}

// ---------- shared GEMM body (R12-proven) ----------
template <int EPI>
__device__ __forceinline__ void gemm_body(
    unsigned short* As, unsigned short* Bs,
    const unsigned short* __restrict__ A, const unsigned short* __restrict__ Bm,
    int K, int lda, int ldb, void* __restrict__ Cout, int ldc,
    const float* __restrict__ bias, int row0, int col0)
{
    const int t = threadIdx.x;
    const int lane = t & 63;
    const int wv = t >> 6;
    const int wm = wv >> 1, wn = wv & 1;
    const int li = lane & 15;
    const int koff = (lane >> 4) * 8;

    f32x4 acc[4][4] = {};

    const int tr = t >> 2;
    const int tc = (t & 3) * 8;
    const unsigned short* ag = A + (size_t)(row0 + tr) * lda + tc;
    const unsigned short* bg = Bm + (size_t)(col0 + tr) * ldb + tc;

    for (int kt = 0; kt < K; kt += 32) {
        gload_lds16(ag,            As + t * 8);
        gload_lds16(ag + 64 * lda, As + 2048 + t * 8);
        gload_lds16(bg,            Bs + t * 8);
        gload_lds16(bg + 64 * ldb, Bs + 2048 + t * 8);
        ag += 32; bg += 32;
        __syncthreads();
        short8 af[4], bf[4];
#pragma unroll
        for (int m = 0; m < 4; ++m)
            af[m] = *(const short8*)&As[(wm * 64 + m * 16 + li) * 32 + koff];
#pragma unroll
        for (int n = 0; n < 4; ++n)
            bf[n] = *(const short8*)&Bs[(wn * 64 + n * 16 + li) * 32 + koff];
#pragma unroll
        for (int m = 0; m < 4; ++m)
#pragma unroll
            for (int n = 0; n < 4; ++n)
                acc[m][n] = __builtin_amdgcn_mfma_f32_16x16x32_bf16(af[m], bf[n], acc[m][n], 0, 0, 0);
        __syncthreads();
    }

#pragma unroll
    for (int m = 0; m < 4; ++m) {
        const int row = row0 + wm * 64 + m * 16 + (lane >> 4) * 4;
#pragma unroll
        for (int n = 0; n < 4; ++n) {
            const int col = col0 + wn * 64 + n * 16 + li;
#pragma unroll
            for (int r = 0; r < 4; ++r) {
                if (EPI == 0) {
                    ((unsigned short*)Cout)[(size_t)(row + r) * ldc + col] = f2bf(acc[m][n][r]);
                } else {
                    ((float*)Cout)[(size_t)(row + r) * ldc + col] = acc[m][n][r] + bias[col];
                }
            }
        }
    }
}

__global__ __launch_bounds__(256, 2) void gemm_qkv(
    const unsigned short* __restrict__ A, const unsigned short* __restrict__ Bm,
    unsigned short* __restrict__ C)
{
    __shared__ unsigned short As[128 * 32];
    __shared__ unsigned short Bs[128 * 32];
    const int bid = blockIdx.y * gridDim.x + blockIdx.x;
    const int nwg = gridDim.x * gridDim.y;
    const int swz = (bid & 7) * (nwg >> 3) + (bid >> 3);
    const int row0 = (swz / gridDim.x) * 128;
    const int col0 = (swz % gridDim.x) * 128;
    gemm_body<0>(As, Bs, A, Bm, NC, NC, NC, C, TC, nullptr, row0, col0);
}

__global__ __launch_bounds__(256, 2) void gemm_heads(
    const unsigned short* __restrict__ outb,
    const unsigned short* __restrict__ wmu, const unsigned short* __restrict__ wls,
    const float* __restrict__ mu_b, const float* __restrict__ ls_b,
    float* __restrict__ out_mu, float* __restrict__ out_ls)
{
    __shared__ unsigned short As[128 * 32];
    __shared__ unsigned short Bs[128 * 32];
    const int bid = blockIdx.y * gridDim.x + blockIdx.x;
    const int nwg = gridDim.x * gridDim.y;
    const int swz = (bid & 7) * (nwg >> 3) + (bid >> 3);
    const int row0 = (swz / gridDim.x) * 128;
    const int col0 = (swz % gridDim.x) * 128;
    const int z = blockIdx.z;
    gemm_body<1>(As, Bs, outb + (z ? 384 : 0), z ? wls : wmu, 384, NC, 384,
                 z ? (void*)out_ls : (void*)out_mu, NC, z ? ls_b : mu_b, row0, col0);
}

// ---------- pack V only (frag-order, R12-proven): v3[bh][kt=m/32][d][m%32] ----------
__global__ __launch_bounds__(256, 4) void pack_v(
    const unsigned short* __restrict__ qkvb, unsigned short* __restrict__ v3)
{
    __shared__ unsigned short tile[64][65];
    const int t = threadIdx.x;
    const int bh = blockIdx.y;
    const int b = bh / NH, h = bh % NH;
    const int m0 = blockIdx.x * 64;
#pragma unroll
    for (int i = 0; i < 2; ++i) {
        int lin = i * 256 + t;
        int mr = lin >> 3;
        int dr = (lin & 7) * 8;
        short8 v = *(const short8*)(qkvb + (size_t)(b * NN + m0 + mr) * TC + 1536 + h * 64 + dr);
#pragma unroll
        for (int j = 0; j < 8; ++j) tile[mr][dr + j] = (unsigned short)v[j];
    }
    __syncthreads();
#pragma unroll
    for (int i = 0; i < 2; ++i) {
        int lin = i * 256 + t;
        int dw = lin >> 3;
        int mw = (lin & 7) * 8;
        short8 v;
#pragma unroll
        for (int j = 0; j < 8; ++j) v[j] = (short)tile[mw + j][dw];
        int kt = (m0 + mw) >> 5;
        int mm = mw & 31;
        *(short8*)(v3 + ((size_t)(bh * 32 + kt) * 64 + dw) * 32 + mm) = v;
    }
}

// ---------- fused attention: R17 base + head-group XCD swizzle (isolated) ----------
// 1-D grid 3072. The 12 blocks sharing a 64KB mask tile (b,nt) map to the SAME XCD
// as consecutive slots -> mask L2-resident for 11/12 readers. Bijective:
// slot=bid>>3, xcd=bid&7, h=slot%12, g12=(slot/12)*8+xcd in [0,256).
__global__ __launch_bounds__(512, 6) void attn_kernel(
    const unsigned short* __restrict__ qkvb, const unsigned short* __restrict__ v3,
    const float* __restrict__ mask, const float* __restrict__ weight,
    float* __restrict__ attn_out, unsigned short* __restrict__ outb)
{
    __shared__ __align__(16) char smem[33024];   // K dbuf 2x16KB | later P[16][1032]
    __shared__ f32x4 po[4][64];                  // PV k-half exchange
    __shared__ float red_max[8][16];
    __shared__ float red_sum[8][16];

    const int t = threadIdx.x;
    const int lane = t & 63;
    const int wv = t >> 6;                 // 0..7
    const int li = lane & 15;
    const int g = lane >> 4;
    const int koff = g * 8;

    // head-group XCD swizzle
    const int bid = blockIdx.x;
    const int xcd = bid & 7, slot = bid >> 3;
    const int h = slot % 12;
    const int g12 = (slot / 12) * 8 + xcd;       // (b,nt) in [0,256)
    const int b = g12 >> 6, nt = g12 & 63;
    const int n0 = nt * 16;
    const int bh = b * NH + h;

    unsigned short* sm = (unsigned short*)smem;

    const float* mrow = mask + (size_t)b * NN * NN + (size_t)(n0 + li) * NN + wv * 16 + g * 4;
    const unsigned short* kgbase = qkvb + (size_t)(b * NN) * TC + 768 + h * 64;

    // q frags via asm loads (in the counted FIFO)
    const unsigned short* qp = qkvb + (size_t)(b * NN + n0 + li) * TC + h * 64 + koff;
    short8 qf0, qf1;
    gload16(qf0, qp);
    gload16(qf1, qp + 32);

    f32x4 acc[8];
    f32x4 mk[2];

    // stage chunk ck: this wave's 16 keys (2 gload_lds, 1KB each) + its mask f32x4
#define KISSUE(c) do {                                                        \
        _Pragma("unroll")                                                     \
        for (int i_ = 0; i_ < 2; ++i_) {                                      \
            int m_ = wv * 16 + i_ * 8 + (lane >> 3);                          \
            int sl_ = (lane & 7) ^ (m_ & 7);                                  \
            const unsigned short* src_ = kgbase + (size_t)((c) * 128 + m_) * TC + sl_ * 8; \
            unsigned short* dst_ = sm + ((c) & 1) * 8192 + wv * 1024 + i_ * 512 + lane * 8; \
            gload_lds16(src_, dst_);                                          \
        }                                                                     \
        gloadf4(mk[(c) & 1], mrow + (c) * 128);                               \
    } while (0)

#define KSTEP(c) do {                                                         \
        const unsigned short* kbuf_ = sm + ((c) & 1) * 8192;                  \
        short8 kf0 = *(const short8*)&kbuf_[(wv * 16 + li) * 64 + ((g ^ (li & 7)) * 8)];       \
        short8 kf1 = *(const short8*)&kbuf_[(wv * 16 + li) * 64 + (((g + 4) ^ (li & 7)) * 8)]; \
        f32x4 ci = mk[(c) & 1] * 96.0f;                                       \
        ci = __builtin_amdgcn_mfma_f32_16x16x32_bf16(kf0, qf0, ci, 0, 0, 0);  \
        ci = __builtin_amdgcn_mfma_f32_16x16x32_bf16(kf1, qf1, ci, 0, 0, 0);  \
        acc[(c)] = ci;                                                        \
    } while (0)

    // ledger: qf(2) + c0(3) + c1(3) = 8; WAITV(3) retires qf+c0; steady 3-in-flight
    KISSUE(0); KISSUE(1);
    WAITV(3);  KSTEP(0); SBAR(); KISSUE(2);
    WAITV(3);  KSTEP(1); SBAR(); KISSUE(3);
    WAITV(3);  KSTEP(2); SBAR(); KISSUE(4);
    WAITV(3);  KSTEP(3); SBAR(); KISSUE(5);
    WAITV(3);  KSTEP(4); SBAR(); KISSUE(6);
    WAITV(3);  KSTEP(5); SBAR(); KISSUE(7);
    WAITV(3);  KSTEP(6);
    WAITV(0);  KSTEP(7);
#undef KISSUE
#undef KSTEP

    // ---- weight prefetch: 8 f32x4 asm loads; latency hides under reduce + barrier
    const float* wbase = weight + b * NN + wv * 16 + g * 4;
    f32x4 wreg[8];
#pragma unroll
    for (int cf = 0; cf < 8; ++cf) gloadf4(wreg[cf], wbase + cf * 128);

    // ---- row max over this wave's 128 keys (acc = s*96; monotone)
    const float scale = 1.0f / 96.0f;
    float rmax = -1e30f;
#pragma unroll
    for (int cf = 0; cf < 8; ++cf) {
#pragma unroll
        for (int r = 0; r < 4; ++r) rmax = fmaxf(rmax, acc[cf][r]);
    }
    rmax = fmaxf(rmax, __shfl_xor(rmax, 16, 64));
    rmax = fmaxf(rmax, __shfl_xor(rmax, 32, 64));
    if (lane < 16) red_max[wv][lane] = rmax;
    __syncthreads();                        // fence: all waves done with K LDS
    {
        float m01 = fmaxf(red_max[0][li], red_max[1][li]);
        float m23 = fmaxf(red_max[2][li], red_max[3][li]);
        float m45 = fmaxf(red_max[4][li], red_max[5][li]);
        float m67 = fmaxf(red_max[6][li], red_max[7][li]);
        rmax = fmaxf(fmaxf(m01, m23), fmaxf(m45, m67)) * scale;
    }

    // ---- p = exp(s-max)*w; stage bf16 p into P (overlays K bufs); weighted row sum
    // wreg ledger: 8 outstanding; WAITV(4) releases wreg0-3, WAITV(0) the rest.
    unsigned short (*P)[1032] = (unsigned short(*)[1032])smem;
    float rsum = 0.f;
    WAITV(4);
#pragma unroll
    for (int cf = 0; cf < 4; ++cf) {
        u16x4 pb;
#pragma unroll
        for (int r = 0; r < 4; ++r) {
            float p = __expf(acc[cf][r] * scale - rmax) * (wreg[cf][r] + 1e-10f);
            rsum += p;
            pb[r] = f2bf(p);
        }
        *(u16x4*)&P[li][cf * 128 + wv * 16 + g * 4] = pb;
    }
    WAITV(0);
#pragma unroll
    for (int cf = 4; cf < 8; ++cf) {
        u16x4 pb;
#pragma unroll
        for (int r = 0; r < 4; ++r) {
            float p = __expf(acc[cf][r] * scale - rmax) * (wreg[cf][r] + 1e-10f);
            rsum += p;
            pb[r] = f2bf(p);
        }
        *(u16x4*)&P[li][cf * 128 + wv * 16 + g * 4] = pb;
    }
    rsum += __shfl_xor(rsum, 16, 64);
    rsum += __shfl_xor(rsum, 32, 64);
    if (lane < 16) red_sum[wv][lane] = rsum;
    __syncthreads();                        // P complete + red_sum ready

    // ---- PV: wave (kh = wv>>2, p4 = wv&3): keys [kh*512,+512), d-cols [p4*16,+16).
    // clean V-only ledger: V0(4),V1(4) -> WAITV(4)/(4)/(4)/(0)
    const int kh = wv >> 2, p4 = wv & 3;
    f32x4 o = {};
    const unsigned short* v3s = v3 + (size_t)bh * 65536 + (size_t)(kh * 16) * 2048
                              + p4 * 512 + li * 32 + g * 8;
    short8 vA[4], vB[4];
#define VISSUE(c, vb2) do {                                                   \
        _Pragma("unroll")                                                     \
        for (int j2 = 0; j2 < 4; ++j2) gload16(vb2[j2], v3s + ((c) * 4 + j2) * 2048); \
    } while (0)
#define VCOMP(c, vb2) do {                                                    \
        __builtin_amdgcn_s_setprio(1);                                        \
        _Pragma("unroll")                                                     \
        for (int j2 = 0; j2 < 4; ++j2) {                                      \
            const int kt = kh * 16 + (c) * 4 + j2;                            \
            short8 pa = *(const short8*)&P[li][kt * 32 + koff];               \
            o = __builtin_amdgcn_mfma_f32_16x16x32_bf16(pa, vb2[j2], o, 0, 0, 0); \
        }                                                                     \
        __builtin_amdgcn_s_setprio(0);                                        \
    } while (0)
    VISSUE(0, vA);
    VISSUE(1, vB);
    WAITV(4);  VCOMP(0, vA); SBAR(); VISSUE(2, vA);
    WAITV(4);  VCOMP(1, vB); SBAR(); VISSUE(3, vB);
    WAITV(4);  VCOMP(2, vA);
    WAITV(0);  VCOMP(3, vB);
#undef VISSUE
#undef VCOMP

    // ---- merge k-halves: waves 4-7 publish, waves 0-3 add + store outb
    if (kh == 1) po[p4][lane] = o;
    __syncthreads();
    if (kh == 0) {
        f32x4 oo = po[p4][lane];
        const int dcol = h * 64 + p4 * 16 + li;
#pragma unroll
        for (int r = 0; r < 4; ++r) {
            const int row = g * 4 + r;
            const float rs = red_sum[0][row] + red_sum[1][row] + red_sum[2][row]
                           + red_sum[3][row] + red_sum[4][row] + red_sum[5][row]
                           + red_sum[6][row] + red_sum[7][row];
            outb[(size_t)(b * NN + n0 + row) * NC + dcol] = f2bf((o[r] + oo[r]) / rs);
        }
    }

    // ---- attn row-stores: wave wv writes rows 2wv, 2wv+1 from LDS P (bf16 -> f32).
    // Per instruction: 64 lanes x 16B = 1KB contiguous = 8 FULL 128B lines.
#pragma unroll
    for (int rr = 0; rr < 2; ++rr) {
        const int row = wv * 2 + rr;
        const float rs = red_sum[0][row] + red_sum[1][row] + red_sum[2][row]
                       + red_sum[3][row] + red_sum[4][row] + red_sum[5][row]
                       + red_sum[6][row] + red_sum[7][row];
        const float rv = 1.0f / rs;
        const unsigned short* prow = &P[row][0];
        float* orow = attn_out + (size_t)bh * NN * NN + (size_t)(n0 + row) * NN;
#pragma unroll
        for (int j = 0; j < 4; ++j) {
            u16x4 pv = *(const u16x4*)&prow[j * 256 + lane * 4];
            f32x4 a4;
#pragma unroll
            for (int r = 0; r < 4; ++r)
                a4[r] = __uint_as_float((unsigned)pv[r] << 16) * rv;
            __builtin_nontemporal_store(a4, (f32x4*)(orow + j * 256 + lane * 4));
        }
    }
}

// ---------- launch ----------
extern "C" void kernel_launch(void* const* d_in, const int* in_sizes, int n_in,
                              void* d_out, int out_size, void* d_ws, size_t ws_size,
                              hipStream_t stream) {
    const float* x      = (const float*)d_in[0];
    const float* mask   = (const float*)d_in[1];
    const float* weight = (const float*)d_in[2];
    const float* qkv_w  = (const float*)d_in[3];
    const float* mu_w   = (const float*)d_in[4];
    const float* mu_b   = (const float*)d_in[5];
    const float* ls_w   = (const float*)d_in[6];
    const float* ls_b   = (const float*)d_in[7];

    char* ws = (char*)d_ws;
    unsigned short* xb   = (unsigned short*)(ws + OFF_XB);
    unsigned short* wq   = (unsigned short*)(ws + OFF_WQ);
    unsigned short* wmu  = (unsigned short*)(ws + OFF_WMU);
    unsigned short* wls  = (unsigned short*)(ws + OFF_WLS);
    unsigned short* qkvb = (unsigned short*)(ws + OFF_QKVB);
    unsigned short* v3   = (unsigned short*)(ws + OFF_V3);
    unsigned short* outb = (unsigned short*)(ws + OFF_OUTB);

    float* out_mu   = (float*)d_out;
    float* out_ls   = out_mu + 3145728;
    float* out_attn = out_mu + 6291456;

    cast_all<<<5376, 256, 0, stream>>>(x, qkv_w, mu_w, ls_w, xb);

    gemm_qkv<<<dim3(TC / 128, 4096 / 128), 256, 0, stream>>>(xb, wq, qkvb);

    pack_v<<<dim3(NN / 64, NB * NH), 256, 0, stream>>>(qkvb, v3);

    attn_kernel<<<3072, 512, 0, stream>>>(
        qkvb, v3, mask, weight, out_attn, outb);

    gemm_heads<<<dim3(NC / 128, 4096 / 128, 2), 256, 0, stream>>>(
        outb, wmu, wls, mu_b, ls_b, out_mu, out_ls);
}

// Round 19
// 133.798 us; speedup vs baseline: 1.0021x; 1.0021x over previous
//
#include <hip/hip_runtime.h>
#include <hip/hip_bf16.h>

// ---------- types ----------
typedef __attribute__((ext_vector_type(8))) short short8;      // 8 x bf16 (4 VGPR) MFMA frag
typedef __attribute__((ext_vector_type(4))) float f32x4;       // MFMA accumulator
typedef __attribute__((ext_vector_type(4))) unsigned short u16x4;

// ---------- constants ----------
#define NB 4
#define NN 1024
#define NC 768
#define NH 12
#define TC 2304

// workspace byte offsets
#define OFF_XB   0ul
#define OFF_WQ   6291456ul
#define OFF_WMU  (OFF_WQ + 3538944ul)
#define OFF_WLS  (OFF_WMU + 589824ul)
#define OFF_QKVB (OFF_WLS + 589824ul)
#define OFF_V3   (OFF_QKVB + 18874368ul)
#define OFF_OUTB (OFF_V3 + 6291456ul)

__device__ __forceinline__ unsigned short f2bf(float f) {
    unsigned int u = __float_as_uint(f);
    u = (u + 0x7FFFu + ((u >> 16) & 1u)) >> 16;
    return (unsigned short)u;
}

__device__ __forceinline__ void gload_lds16(const unsigned short* g, unsigned short* l) {
    __builtin_amdgcn_global_load_lds(
        (const __attribute__((address_space(1))) unsigned int*)g,
        (__attribute__((address_space(3))) unsigned int*)l, 16, 0, 0);
}

__device__ __forceinline__ void gload16(short8& dst, const unsigned short* p) {
    asm volatile("global_load_dwordx4 %0, %1, off" : "=v"(dst) : "v"(p));
}
__device__ __forceinline__ void gloadf4(f32x4& dst, const float* p) {
    asm volatile("global_load_dwordx4 %0, %1, off" : "=v"(dst) : "v"(p));
}
#define WAITV(N) do { asm volatile("s_waitcnt vmcnt(" #N ")" ::: "memory"); \
                      __builtin_amdgcn_sched_barrier(0); } while (0)
#define SBAR()   __builtin_amdgcn_sched_barrier(0)

// ---------- fused cast f32 -> bf16 ----------
__global__ void cast_all(const float* __restrict__ x, const float* __restrict__ qkv_w,
                         const float* __restrict__ mu_w, const float* __restrict__ ls_w,
                         unsigned short* __restrict__ dst) {
    int i = blockIdx.x * blockDim.x + threadIdx.x;
    const float* src; int off;
    if (i < 786432)            { src = x;     off = i; }
    else if (i < 1228800)      { src = qkv_w; off = i - 786432; }
    else if (i < 1302528)      { src = mu_w;  off = i - 1228800; }
    else                       { src = ls_w;  off = i - 1302528; }
    f32x4 v = ((const f32x4*)src)[off];
    u16x4 o;
#pragma unroll
    for (int j = 0; j < 4; ++j) o[j] = f2bf(v[j]);
    ((u16x4*)dst)[i] = o;
}

// ---------- shared GEMM body; LDS-staged FULL-LINE epilogues ----------
// EPI=0: bf16 out (plain full-line stores; data is re-read downstream -> keep cacheable).
// EPI=1: f32 out + bias[col] (plain full-line stores).
template <int EPI>
__device__ __forceinline__ void gemm_body(
    unsigned short* smem,                  // 16KB: As = smem, Bs = smem+4096
    const unsigned short* __restrict__ A, const unsigned short* __restrict__ Bm,
    int K, int lda, int ldb, void* __restrict__ Cout, int ldc,
    const float* __restrict__ bias, int row0, int col0)
{
    unsigned short* As = smem;
    unsigned short* Bs = smem + 4096;
    const int t = threadIdx.x;
    const int lane = t & 63;
    const int wv = t >> 6;
    const int wm = wv >> 1, wn = wv & 1;
    const int li = lane & 15;
    const int g = lane >> 4;
    const int koff = g * 8;

    f32x4 acc[4][4] = {};

    const int tr = t >> 2;
    const int tc = (t & 3) * 8;
    const unsigned short* ag = A + (size_t)(row0 + tr) * lda + tc;
    const unsigned short* bg = Bm + (size_t)(col0 + tr) * ldb + tc;

    for (int kt = 0; kt < K; kt += 32) {
        gload_lds16(ag,            As + t * 8);
        gload_lds16(ag + 64 * lda, As + 2048 + t * 8);
        gload_lds16(bg,            Bs + t * 8);
        gload_lds16(bg + 64 * ldb, Bs + 2048 + t * 8);
        ag += 32; bg += 32;
        __syncthreads();
        short8 af[4], bf[4];
#pragma unroll
        for (int m = 0; m < 4; ++m)
            af[m] = *(const short8*)&As[(wm * 64 + m * 16 + li) * 32 + koff];
#pragma unroll
        for (int n = 0; n < 4; ++n)
            bf[n] = *(const short8*)&Bs[(wn * 64 + n * 16 + li) * 32 + koff];
#pragma unroll
        for (int m = 0; m < 4; ++m)
#pragma unroll
            for (int n = 0; n < 4; ++n)
                acc[m][n] = __builtin_amdgcn_mfma_f32_16x16x32_bf16(af[m], bf[n], acc[m][n], 0, 0, 0);
        __syncthreads();
    }
    // K-loop ends with syncthreads -> As/Bs free for C staging

    if (EPI == 0) {
        // 2 phases; phase s stages m = {2s, 2s+1} (64 rows) as bf16 [64][128] = 16KB
        unsigned short (*Cs)[128] = (unsigned short(*)[128])smem;
#pragma unroll
        for (int s = 0; s < 2; ++s) {
            if (s) __syncthreads();        // protect previous phase's reads
#pragma unroll
            for (int mm = 0; mm < 2; ++mm) {
                const int m = 2 * s + mm;
#pragma unroll
                for (int n = 0; n < 4; ++n)
#pragma unroll
                    for (int r = 0; r < 4; ++r)
                        Cs[wm * 32 + mm * 16 + g * 4 + r][wn * 64 + n * 16 + li]
                            = f2bf(acc[m][n][r]);
            }
            __syncthreads();
            // write 64 rows x 256B: lanes 0-15 = one row segment (2 full 128B lines)
#pragma unroll
            for (int p = 0; p < 4; ++p) {
                const int lr = p * 16 + (t >> 4);
                const int gr = row0 + (lr >> 5) * 64 + (2 * s + ((lr >> 4) & 1)) * 16 + (lr & 15);
                short8 v = *(const short8*)&Cs[lr][(t & 15) * 8];
                *(short8*)((unsigned short*)Cout + (size_t)gr * ldc + col0 + (t & 15) * 8) = v;
            }
        }
    } else {
        // 4 phases; phase s stages m = s (32 rows) as f32 [32][128] = 16KB
        float (*Cf)[128] = (float(*)[128])smem;
        const f32x4 bv = *(const f32x4*)&bias[col0 + (t & 31) * 4];
#pragma unroll
        for (int s = 0; s < 4; ++s) {
            if (s) __syncthreads();
#pragma unroll
            for (int n = 0; n < 4; ++n)
#pragma unroll
                for (int r = 0; r < 4; ++r)
                    Cf[wm * 16 + g * 4 + r][wn * 64 + n * 16 + li] = acc[s][n][r];
            __syncthreads();
            // write 32 rows x 512B: lanes (t&31) cover one row segment (4 full lines)
#pragma unroll
            for (int p = 0; p < 4; ++p) {
                const int lr = p * 8 + (t >> 5);
                const int gr = row0 + (lr >> 4) * 64 + s * 16 + (lr & 15);
                f32x4 v = *(const f32x4*)&Cf[lr][(t & 31) * 4];
#pragma unroll
                for (int r = 0; r < 4; ++r) v[r] += bv[r];
                *(f32x4*)((float*)Cout + (size_t)gr * ldc + col0 + (t & 31) * 4) = v;
            }
        }
    }
}

__global__ __launch_bounds__(256, 2) void gemm_qkv(
    const unsigned short* __restrict__ A, const unsigned short* __restrict__ Bm,
    unsigned short* __restrict__ C)
{
    __shared__ __align__(16) unsigned short smem[8192];
    const int bid = blockIdx.y * gridDim.x + blockIdx.x;
    const int nwg = gridDim.x * gridDim.y;
    const int swz = (bid & 7) * (nwg >> 3) + (bid >> 3);
    const int row0 = (swz / gridDim.x) * 128;
    const int col0 = (swz % gridDim.x) * 128;
    gemm_body<0>(smem, A, Bm, NC, NC, NC, C, TC, nullptr, row0, col0);
}

__global__ __launch_bounds__(256, 2) void gemm_heads(
    const unsigned short* __restrict__ outb,
    const unsigned short* __restrict__ wmu, const unsigned short* __restrict__ wls,
    const float* __restrict__ mu_b, const float* __restrict__ ls_b,
    float* __restrict__ out_mu, float* __restrict__ out_ls)
{
    __shared__ __align__(16) unsigned short smem[8192];
    const int bid = blockIdx.y * gridDim.x + blockIdx.x;
    const int nwg = gridDim.x * gridDim.y;
    const int swz = (bid & 7) * (nwg >> 3) + (bid >> 3);
    const int row0 = (swz / gridDim.x) * 128;
    const int col0 = (swz % gridDim.x) * 128;
    const int z = blockIdx.z;
    gemm_body<1>(smem, outb + (z ? 384 : 0), z ? wls : wmu, 384, NC, 384,
                 z ? (void*)out_ls : (void*)out_mu, NC, z ? ls_b : mu_b, row0, col0);
}

// ---------- pack V only (frag-order, R12-proven): v3[bh][kt=m/32][d][m%32] ----------
__global__ __launch_bounds__(256, 4) void pack_v(
    const unsigned short* __restrict__ qkvb, unsigned short* __restrict__ v3)
{
    __shared__ unsigned short tile[64][65];
    const int t = threadIdx.x;
    const int bh = blockIdx.y;
    const int b = bh / NH, h = bh % NH;
    const int m0 = blockIdx.x * 64;
#pragma unroll
    for (int i = 0; i < 2; ++i) {
        int lin = i * 256 + t;
        int mr = lin >> 3;
        int dr = (lin & 7) * 8;
        short8 v = *(const short8*)(qkvb + (size_t)(b * NN + m0 + mr) * TC + 1536 + h * 64 + dr);
#pragma unroll
        for (int j = 0; j < 8; ++j) tile[mr][dr + j] = (unsigned short)v[j];
    }
    __syncthreads();
#pragma unroll
    for (int i = 0; i < 2; ++i) {
        int lin = i * 256 + t;
        int dw = lin >> 3;
        int mw = (lin & 7) * 8;
        short8 v;
#pragma unroll
        for (int j = 0; j < 8; ++j) v[j] = (short)tile[mw + j][dw];
        int kt = (m0 + mw) >> 5;
        int mm = mw & 31;
        *(short8*)(v3 + ((size_t)(bh * 32 + kt) * 64 + dw) * 32 + mm) = v;
    }
}

// ---------- fused attention (R17-proven, byte-identical) ----------
__global__ __launch_bounds__(512, 6) void attn_kernel(
    const unsigned short* __restrict__ qkvb, const unsigned short* __restrict__ v3,
    const float* __restrict__ mask, const float* __restrict__ weight,
    float* __restrict__ attn_out, unsigned short* __restrict__ outb)
{
    __shared__ __align__(16) char smem[33024];   // K dbuf 2x16KB | later P[16][1032]
    __shared__ f32x4 po[4][64];                  // PV k-half exchange
    __shared__ float red_max[8][16];
    __shared__ float red_sum[8][16];

    const int t = threadIdx.x;
    const int lane = t & 63;
    const int wv = t >> 6;                 // 0..7
    const int li = lane & 15;
    const int g = lane >> 4;
    const int koff = g * 8;
    const int bh = blockIdx.y;
    const int b = bh / NH, h = bh % NH;
    const int n0 = blockIdx.x * 16;

    unsigned short* sm = (unsigned short*)smem;

    const float* mrow = mask + (size_t)b * NN * NN + (size_t)(n0 + li) * NN + wv * 16 + g * 4;
    const unsigned short* kgbase = qkvb + (size_t)(b * NN) * TC + 768 + h * 64;

    const unsigned short* qp = qkvb + (size_t)(b * NN + n0 + li) * TC + h * 64 + koff;
    short8 qf0, qf1;
    gload16(qf0, qp);
    gload16(qf1, qp + 32);

    f32x4 acc[8];
    f32x4 mk[2];

#define KISSUE(c) do {                                                        \
        _Pragma("unroll")                                                     \
        for (int i_ = 0; i_ < 2; ++i_) {                                      \
            int m_ = wv * 16 + i_ * 8 + (lane >> 3);                          \
            int sl_ = (lane & 7) ^ (m_ & 7);                                  \
            const unsigned short* src_ = kgbase + (size_t)((c) * 128 + m_) * TC + sl_ * 8; \
            unsigned short* dst_ = sm + ((c) & 1) * 8192 + wv * 1024 + i_ * 512 + lane * 8; \
            gload_lds16(src_, dst_);                                          \
        }                                                                     \
        gloadf4(mk[(c) & 1], mrow + (c) * 128);                               \
    } while (0)

#define KSTEP(c) do {                                                         \
        const unsigned short* kbuf_ = sm + ((c) & 1) * 8192;                  \
        short8 kf0 = *(const short8*)&kbuf_[(wv * 16 + li) * 64 + ((g ^ (li & 7)) * 8)];       \
        short8 kf1 = *(const short8*)&kbuf_[(wv * 16 + li) * 64 + (((g + 4) ^ (li & 7)) * 8)]; \
        f32x4 ci = mk[(c) & 1] * 96.0f;                                       \
        ci = __builtin_amdgcn_mfma_f32_16x16x32_bf16(kf0, qf0, ci, 0, 0, 0);  \
        ci = __builtin_amdgcn_mfma_f32_16x16x32_bf16(kf1, qf1, ci, 0, 0, 0);  \
        acc[(c)] = ci;                                                        \
    } while (0)

    KISSUE(0); KISSUE(1);
    WAITV(3);  KSTEP(0); SBAR(); KISSUE(2);
    WAITV(3);  KSTEP(1); SBAR(); KISSUE(3);
    WAITV(3);  KSTEP(2); SBAR(); KISSUE(4);
    WAITV(3);  KSTEP(3); SBAR(); KISSUE(5);
    WAITV(3);  KSTEP(4); SBAR(); KISSUE(6);
    WAITV(3);  KSTEP(5); SBAR(); KISSUE(7);
    WAITV(3);  KSTEP(6);
    WAITV(0);  KSTEP(7);
#undef KISSUE
#undef KSTEP

    const float* wbase = weight + b * NN + wv * 16 + g * 4;
    f32x4 wreg[8];
#pragma unroll
    for (int cf = 0; cf < 8; ++cf) gloadf4(wreg[cf], wbase + cf * 128);

    const float scale = 1.0f / 96.0f;
    float rmax = -1e30f;
#pragma unroll
    for (int cf = 0; cf < 8; ++cf) {
#pragma unroll
        for (int r = 0; r < 4; ++r) rmax = fmaxf(rmax, acc[cf][r]);
    }
    rmax = fmaxf(rmax, __shfl_xor(rmax, 16, 64));
    rmax = fmaxf(rmax, __shfl_xor(rmax, 32, 64));
    if (lane < 16) red_max[wv][lane] = rmax;
    __syncthreads();
    {
        float m01 = fmaxf(red_max[0][li], red_max[1][li]);
        float m23 = fmaxf(red_max[2][li], red_max[3][li]);
        float m45 = fmaxf(red_max[4][li], red_max[5][li]);
        float m67 = fmaxf(red_max[6][li], red_max[7][li]);
        rmax = fmaxf(fmaxf(m01, m23), fmaxf(m45, m67)) * scale;
    }

    unsigned short (*P)[1032] = (unsigned short(*)[1032])smem;
    float rsum = 0.f;
    WAITV(4);
#pragma unroll
    for (int cf = 0; cf < 4; ++cf) {
        u16x4 pb;
#pragma unroll
        for (int r = 0; r < 4; ++r) {
            float p = __expf(acc[cf][r] * scale - rmax) * (wreg[cf][r] + 1e-10f);
            rsum += p;
            pb[r] = f2bf(p);
        }
        *(u16x4*)&P[li][cf * 128 + wv * 16 + g * 4] = pb;
    }
    WAITV(0);
#pragma unroll
    for (int cf = 4; cf < 8; ++cf) {
        u16x4 pb;
#pragma unroll
        for (int r = 0; r < 4; ++r) {
            float p = __expf(acc[cf][r] * scale - rmax) * (wreg[cf][r] + 1e-10f);
            rsum += p;
            pb[r] = f2bf(p);
        }
        *(u16x4*)&P[li][cf * 128 + wv * 16 + g * 4] = pb;
    }
    rsum += __shfl_xor(rsum, 16, 64);
    rsum += __shfl_xor(rsum, 32, 64);
    if (lane < 16) red_sum[wv][lane] = rsum;
    __syncthreads();

    const int kh = wv >> 2, p4 = wv & 3;
    f32x4 o = {};
    const unsigned short* v3s = v3 + (size_t)bh * 65536 + (size_t)(kh * 16) * 2048
                              + p4 * 512 + li * 32 + g * 8;
    short8 vA[4], vB[4];
#define VISSUE(c, vb2) do {                                                   \
        _Pragma("unroll")                                                     \
        for (int j2 = 0; j2 < 4; ++j2) gload16(vb2[j2], v3s + ((c) * 4 + j2) * 2048); \
    } while (0)
#define VCOMP(c, vb2) do {                                                    \
        __builtin_amdgcn_s_setprio(1);                                        \
        _Pragma("unroll")                                                     \
        for (int j2 = 0; j2 < 4; ++j2) {                                      \
            const int kt = kh * 16 + (c) * 4 + j2;                            \
            short8 pa = *(const short8*)&P[li][kt * 32 + koff];               \
            o = __builtin_amdgcn_mfma_f32_16x16x32_bf16(pa, vb2[j2], o, 0, 0, 0); \
        }                                                                     \
        __builtin_amdgcn_s_setprio(0);                                        \
    } while (0)
    VISSUE(0, vA);
    VISSUE(1, vB);
    WAITV(4);  VCOMP(0, vA); SBAR(); VISSUE(2, vA);
    WAITV(4);  VCOMP(1, vB); SBAR(); VISSUE(3, vB);
    WAITV(4);  VCOMP(2, vA);
    WAITV(0);  VCOMP(3, vB);
#undef VISSUE
#undef VCOMP

    if (kh == 1) po[p4][lane] = o;
    __syncthreads();
    if (kh == 0) {
        f32x4 oo = po[p4][lane];
        const int dcol = h * 64 + p4 * 16 + li;
#pragma unroll
        for (int r = 0; r < 4; ++r) {
            const int row = g * 4 + r;
            const float rs = red_sum[0][row] + red_sum[1][row] + red_sum[2][row]
                           + red_sum[3][row] + red_sum[4][row] + red_sum[5][row]
                           + red_sum[6][row] + red_sum[7][row];
            outb[(size_t)(b * NN + n0 + row) * NC + dcol] = f2bf((o[r] + oo[r]) / rs);
        }
    }

    // attn row-stores: wave wv writes rows 2wv, 2wv+1 from LDS P (bf16 -> f32), full lines
#pragma unroll
    for (int rr = 0; rr < 2; ++rr) {
        const int row = wv * 2 + rr;
        const float rs = red_sum[0][row] + red_sum[1][row] + red_sum[2][row]
                       + red_sum[3][row] + red_sum[4][row] + red_sum[5][row]
                       + red_sum[6][row] + red_sum[7][row];
        const float rv = 1.0f / rs;
        const unsigned short* prow = &P[row][0];
        float* orow = attn_out + (size_t)bh * NN * NN + (size_t)(n0 + row) * NN;
#pragma unroll
        for (int j = 0; j < 4; ++j) {
            u16x4 pv = *(const u16x4*)&prow[j * 256 + lane * 4];
            f32x4 a4;
#pragma unroll
            for (int r = 0; r < 4; ++r)
                a4[r] = __uint_as_float((unsigned)pv[r] << 16) * rv;
            __builtin_nontemporal_store(a4, (f32x4*)(orow + j * 256 + lane * 4));
        }
    }
}

// ---------- launch ----------
extern "C" void kernel_launch(void* const* d_in, const int* in_sizes, int n_in,
                              void* d_out, int out_size, void* d_ws, size_t ws_size,
                              hipStream_t stream) {
    const float* x      = (const float*)d_in[0];
    const float* mask   = (const float*)d_in[1];
    const float* weight = (const float*)d_in[2];
    const float* qkv_w  = (const float*)d_in[3];
    const float* mu_w   = (const float*)d_in[4];
    const float* mu_b   = (const float*)d_in[5];
    const float* ls_w   = (const float*)d_in[6];
    const float* ls_b   = (const float*)d_in[7];

    char* ws = (char*)d_ws;
    unsigned short* xb   = (unsigned short*)(ws + OFF_XB);
    unsigned short* wq   = (unsigned short*)(ws + OFF_WQ);
    unsigned short* wmu  = (unsigned short*)(ws + OFF_WMU);
    unsigned short* wls  = (unsigned short*)(ws + OFF_WLS);
    unsigned short* qkvb = (unsigned short*)(ws + OFF_QKVB);
    unsigned short* v3   = (unsigned short*)(ws + OFF_V3);
    unsigned short* outb = (unsigned short*)(ws + OFF_OUTB);

    float* out_mu   = (float*)d_out;
    float* out_ls   = out_mu + 3145728;
    float* out_attn = out_mu + 6291456;

    cast_all<<<5376, 256, 0, stream>>>(x, qkv_w, mu_w, ls_w, xb);

    gemm_qkv<<<dim3(TC / 128, 4096 / 128), 256, 0, stream>>>(xb, wq, qkvb);

    pack_v<<<dim3(NN / 64, NB * NH), 256, 0, stream>>>(qkvb, v3);

    attn_kernel<<<dim3(NN / 16, NB * NH), 512, 0, stream>>>(
        qkvb, v3, mask, weight, out_attn, outb);

    gemm_heads<<<dim3(NC / 128, 4096 / 128, 2), 256, 0, stream>>>(
        outb, wmu, wls, mu_b, ls_b, out_mu, out_ls);
}

// Round 21
// 133.660 us; speedup vs baseline: 1.0032x; 1.0010x over previous
//
#include <hip/hip_runtime.h>
#include <hip/hip_bf16.h>

// ---------- types ----------
typedef __attribute__((ext_vector_type(8))) short short8;      // 8 x bf16 (4 VGPR) MFMA frag
typedef __attribute__((ext_vector_type(4))) float f32x4;       // MFMA accumulator
typedef __attribute__((ext_vector_type(4))) unsigned short u16x4;

// ---------- constants ----------
#define NB 4
#define NN 1024
#define NC 768
#define NH 12
#define TC 2304

// workspace byte offsets
#define OFF_XB   0ul
#define OFF_WQ   6291456ul
#define OFF_WMU  (OFF_WQ + 3538944ul)
#define OFF_WLS  (OFF_WMU + 589824ul)
#define OFF_QKVB (OFF_WLS + 589824ul)
#define OFF_V3   (OFF_QKVB + 18874368ul)
#define OFF_OUTB (OFF_V3 + 6291456ul)

__device__ __forceinline__ unsigned short f2bf(float f) {
    unsigned int u = __float_as_uint(f);
    u = (u + 0x7FFFu + ((u >> 16) & 1u)) >> 16;
    return (unsigned short)u;
}

__device__ __forceinline__ void gload_lds16(const unsigned short* g, unsigned short* l) {
    __builtin_amdgcn_global_load_lds(
        (const __attribute__((address_space(1))) unsigned int*)g,
        (__attribute__((address_space(3))) unsigned int*)l, 16, 0, 0);
}

__device__ __forceinline__ void gload16(short8& dst, const unsigned short* p) {
    asm volatile("global_load_dwordx4 %0, %1, off" : "=v"(dst) : "v"(p));
}
__device__ __forceinline__ void gloadf4(f32x4& dst, const float* p) {
    asm volatile("global_load_dwordx4 %0, %1, off" : "=v"(dst) : "v"(p));
}
#define WAITV(N) do { asm volatile("s_waitcnt vmcnt(" #N ")" ::: "memory"); \
                      __builtin_amdgcn_sched_barrier(0); } while (0)
#define SBAR()   __builtin_amdgcn_sched_barrier(0)

// ---------- fused cast f32 -> bf16 ----------
__global__ void cast_all(const float* __restrict__ x, const float* __restrict__ qkv_w,
                         const float* __restrict__ mu_w, const float* __restrict__ ls_w,
                         unsigned short* __restrict__ dst) {
    int i = blockIdx.x * blockDim.x + threadIdx.x;
    const float* src; int off;
    if (i < 786432)            { src = x;     off = i; }
    else if (i < 1228800)      { src = qkv_w; off = i - 786432; }
    else if (i < 1302528)      { src = mu_w;  off = i - 1228800; }
    else                       { src = ls_w;  off = i - 1302528; }
    f32x4 v = ((const f32x4*)src)[off];
    u16x4 o;
#pragma unroll
    for (int j = 0; j < 4; ++j) o[j] = f2bf(v[j]);
    ((u16x4*)dst)[i] = o;
}

// ---------- shared GEMM body; LDS-staged FULL-LINE epilogues (R19-proven) ----------
template <int EPI>
__device__ __forceinline__ void gemm_body(
    unsigned short* smem,                  // 16KB: As = smem, Bs = smem+4096
    const unsigned short* __restrict__ A, const unsigned short* __restrict__ Bm,
    int K, int lda, int ldb, void* __restrict__ Cout, int ldc,
    const float* __restrict__ bias, int row0, int col0)
{
    unsigned short* As = smem;
    unsigned short* Bs = smem + 4096;
    const int t = threadIdx.x;
    const int lane = t & 63;
    const int wv = t >> 6;
    const int wm = wv >> 1, wn = wv & 1;
    const int li = lane & 15;
    const int g = lane >> 4;
    const int koff = g * 8;

    f32x4 acc[4][4] = {};

    const int tr = t >> 2;
    const int tc = (t & 3) * 8;
    const unsigned short* ag = A + (size_t)(row0 + tr) * lda + tc;
    const unsigned short* bg = Bm + (size_t)(col0 + tr) * ldb + tc;

    for (int kt = 0; kt < K; kt += 32) {
        gload_lds16(ag,            As + t * 8);
        gload_lds16(ag + 64 * lda, As + 2048 + t * 8);
        gload_lds16(bg,            Bs + t * 8);
        gload_lds16(bg + 64 * ldb, Bs + 2048 + t * 8);
        ag += 32; bg += 32;
        __syncthreads();
        short8 af[4], bf[4];
#pragma unroll
        for (int m = 0; m < 4; ++m)
            af[m] = *(const short8*)&As[(wm * 64 + m * 16 + li) * 32 + koff];
#pragma unroll
        for (int n = 0; n < 4; ++n)
            bf[n] = *(const short8*)&Bs[(wn * 64 + n * 16 + li) * 32 + koff];
#pragma unroll
        for (int m = 0; m < 4; ++m)
#pragma unroll
            for (int n = 0; n < 4; ++n)
                acc[m][n] = __builtin_amdgcn_mfma_f32_16x16x32_bf16(af[m], bf[n], acc[m][n], 0, 0, 0);
        __syncthreads();
    }

    if (EPI == 0) {
        unsigned short (*Cs)[128] = (unsigned short(*)[128])smem;
#pragma unroll
        for (int s = 0; s < 2; ++s) {
            if (s) __syncthreads();
#pragma unroll
            for (int mm = 0; mm < 2; ++mm) {
                const int m = 2 * s + mm;
#pragma unroll
                for (int n = 0; n < 4; ++n)
#pragma unroll
                    for (int r = 0; r < 4; ++r)
                        Cs[wm * 32 + mm * 16 + g * 4 + r][wn * 64 + n * 16 + li]
                            = f2bf(acc[m][n][r]);
            }
            __syncthreads();
#pragma unroll
            for (int p = 0; p < 4; ++p) {
                const int lr = p * 16 + (t >> 4);
                const int gr = row0 + (lr >> 5) * 64 + (2 * s + ((lr >> 4) & 1)) * 16 + (lr & 15);
                short8 v = *(const short8*)&Cs[lr][(t & 15) * 8];
                *(short8*)((unsigned short*)Cout + (size_t)gr * ldc + col0 + (t & 15) * 8) = v;
            }
        }
    } else {
        float (*Cf)[128] = (float(*)[128])smem;
        const f32x4 bv = *(const f32x4*)&bias[col0 + (t & 31) * 4];
#pragma unroll
        for (int s = 0; s < 4; ++s) {
            if (s) __syncthreads();
#pragma unroll
            for (int n = 0; n < 4; ++n)
#pragma unroll
                for (int r = 0; r < 4; ++r)
                    Cf[wm * 16 + g * 4 + r][wn * 64 + n * 16 + li] = acc[s][n][r];
            __syncthreads();
#pragma unroll
            for (int p = 0; p < 4; ++p) {
                const int lr = p * 8 + (t >> 5);
                const int gr = row0 + (lr >> 4) * 64 + s * 16 + (lr & 15);
                f32x4 v = *(const f32x4*)&Cf[lr][(t & 31) * 4];
#pragma unroll
                for (int r = 0; r < 4; ++r) v[r] += bv[r];
                *(f32x4*)((float*)Cout + (size_t)gr * ldc + col0 + (t & 31) * 4) = v;
            }
        }
    }
}

__global__ __launch_bounds__(256, 2) void gemm_qkv(
    const unsigned short* __restrict__ A, const unsigned short* __restrict__ Bm,
    unsigned short* __restrict__ C)
{
    __shared__ __align__(16) unsigned short smem[8192];
    const int bid = blockIdx.y * gridDim.x + blockIdx.x;
    const int nwg = gridDim.x * gridDim.y;
    const int swz = (bid & 7) * (nwg >> 3) + (bid >> 3);
    const int row0 = (swz / gridDim.x) * 128;
    const int col0 = (swz % gridDim.x) * 128;
    gemm_body<0>(smem, A, Bm, NC, NC, NC, C, TC, nullptr, row0, col0);
}

__global__ __launch_bounds__(256, 2) void gemm_heads(
    const unsigned short* __restrict__ outb,
    const unsigned short* __restrict__ wmu, const unsigned short* __restrict__ wls,
    const float* __restrict__ mu_b, const float* __restrict__ ls_b,
    float* __restrict__ out_mu, float* __restrict__ out_ls)
{
    __shared__ __align__(16) unsigned short smem[8192];
    const int bid = blockIdx.y * gridDim.x + blockIdx.x;
    const int nwg = gridDim.x * gridDim.y;
    const int swz = (bid & 7) * (nwg >> 3) + (bid >> 3);
    const int row0 = (swz / gridDim.x) * 128;
    const int col0 = (swz % gridDim.x) * 128;
    const int z = blockIdx.z;
    gemm_body<1>(smem, outb + (z ? 384 : 0), z ? wls : wmu, 384, NC, 384,
                 z ? (void*)out_ls : (void*)out_mu, NC, z ? ls_b : mu_b, row0, col0);
}

// ---------- pack V only (frag-order, R12-proven): v3[bh][kt=m/32][d][m%32] ----------
__global__ __launch_bounds__(256, 4) void pack_v(
    const unsigned short* __restrict__ qkvb, unsigned short* __restrict__ v3)
{
    __shared__ unsigned short tile[64][65];
    const int t = threadIdx.x;
    const int bh = blockIdx.y;
    const int b = bh / NH, h = bh % NH;
    const int m0 = blockIdx.x * 64;
#pragma unroll
    for (int i = 0; i < 2; ++i) {
        int lin = i * 256 + t;
        int mr = lin >> 3;
        int dr = (lin & 7) * 8;
        short8 v = *(const short8*)(qkvb + (size_t)(b * NN + m0 + mr) * TC + 1536 + h * 64 + dr);
#pragma unroll
        for (int j = 0; j < 8; ++j) tile[mr][dr + j] = (unsigned short)v[j];
    }
    __syncthreads();
#pragma unroll
    for (int i = 0; i < 2; ++i) {
        int lin = i * 256 + t;
        int dw = lin >> 3;
        int mw = (lin & 7) * 8;
        short8 v;
#pragma unroll
        for (int j = 0; j < 8; ++j) v[j] = (short)tile[mw + j][dw];
        int kt = (m0 + mw) >> 5;
        int mm = mw & 31;
        *(short8*)(v3 + ((size_t)(bh * 32 + kt) * 64 + dw) * 32 + mm) = v;
    }
}

// ---------- fused attention (R17/R19-proven, __launch_bounds__(512,6)) ----------
__global__ __launch_bounds__(512, 6) void attn_kernel(
    const unsigned short* __restrict__ qkvb, const unsigned short* __restrict__ v3,
    const float* __restrict__ mask, const float* __restrict__ weight,
    float* __restrict__ attn_out, unsigned short* __restrict__ outb)
{
    __shared__ __align__(16) char smem[33024];   // K dbuf 2x16KB | later P[16][1032]
    __shared__ f32x4 po[4][64];                  // PV k-half exchange
    __shared__ float red_max[8][16];
    __shared__ float red_sum[8][16];

    const int t = threadIdx.x;
    const int lane = t & 63;
    const int wv = t >> 6;                 // 0..7
    const int li = lane & 15;
    const int g = lane >> 4;
    const int koff = g * 8;
    const int bh = blockIdx.y;
    const int b = bh / NH, h = bh % NH;
    const int n0 = blockIdx.x * 16;

    unsigned short* sm = (unsigned short*)smem;

    const float* mrow = mask + (size_t)b * NN * NN + (size_t)(n0 + li) * NN + wv * 16 + g * 4;
    const unsigned short* kgbase = qkvb + (size_t)(b * NN) * TC + 768 + h * 64;

    const unsigned short* qp = qkvb + (size_t)(b * NN + n0 + li) * TC + h * 64 + koff;
    short8 qf0, qf1;
    gload16(qf0, qp);
    gload16(qf1, qp + 32);

    f32x4 acc[8];
    f32x4 mk[2];

#define KISSUE(c) do {                                                        \
        _Pragma("unroll")                                                     \
        for (int i_ = 0; i_ < 2; ++i_) {                                      \
            int m_ = wv * 16 + i_ * 8 + (lane >> 3);                          \
            int sl_ = (lane & 7) ^ (m_ & 7);                                  \
            const unsigned short* src_ = kgbase + (size_t)((c) * 128 + m_) * TC + sl_ * 8; \
            unsigned short* dst_ = sm + ((c) & 1) * 8192 + wv * 1024 + i_ * 512 + lane * 8; \
            gload_lds16(src_, dst_);                                          \
        }                                                                     \
        gloadf4(mk[(c) & 1], mrow + (c) * 128);                               \
    } while (0)

#define KSTEP(c) do {                                                         \
        const unsigned short* kbuf_ = sm + ((c) & 1) * 8192;                  \
        short8 kf0 = *(const short8*)&kbuf_[(wv * 16 + li) * 64 + ((g ^ (li & 7)) * 8)];       \
        short8 kf1 = *(const short8*)&kbuf_[(wv * 16 + li) * 64 + (((g + 4) ^ (li & 7)) * 8)]; \
        f32x4 ci = mk[(c) & 1] * 96.0f;                                       \
        ci = __builtin_amdgcn_mfma_f32_16x16x32_bf16(kf0, qf0, ci, 0, 0, 0);  \
        ci = __builtin_amdgcn_mfma_f32_16x16x32_bf16(kf1, qf1, ci, 0, 0, 0);  \
        acc[(c)] = ci;                                                        \
    } while (0)

    KISSUE(0); KISSUE(1);
    WAITV(3);  KSTEP(0); SBAR(); KISSUE(2);
    WAITV(3);  KSTEP(1); SBAR(); KISSUE(3);
    WAITV(3);  KSTEP(2); SBAR(); KISSUE(4);
    WAITV(3);  KSTEP(3); SBAR(); KISSUE(5);
    WAITV(3);  KSTEP(4); SBAR(); KISSUE(6);
    WAITV(3);  KSTEP(5); SBAR(); KISSUE(7);
    WAITV(3);  KSTEP(6);
    WAITV(0);  KSTEP(7);
#undef KISSUE
#undef KSTEP

    const float* wbase = weight + b * NN + wv * 16 + g * 4;
    f32x4 wreg[8];
#pragma unroll
    for (int cf = 0; cf < 8; ++cf) gloadf4(wreg[cf], wbase + cf * 128);

    const float scale = 1.0f / 96.0f;
    float rmax = -1e30f;
#pragma unroll
    for (int cf = 0; cf < 8; ++cf) {
#pragma unroll
        for (int r = 0; r < 4; ++r) rmax = fmaxf(rmax, acc[cf][r]);
    }
    rmax = fmaxf(rmax, __shfl_xor(rmax, 16, 64));
    rmax = fmaxf(rmax, __shfl_xor(rmax, 32, 64));
    if (lane < 16) red_max[wv][lane] = rmax;
    __syncthreads();
    {
        float m01 = fmaxf(red_max[0][li], red_max[1][li]);
        float m23 = fmaxf(red_max[2][li], red_max[3][li]);
        float m45 = fmaxf(red_max[4][li], red_max[5][li]);
        float m67 = fmaxf(red_max[6][li], red_max[7][li]);
        rmax = fmaxf(fmaxf(m01, m23), fmaxf(m45, m67)) * scale;
    }

    unsigned short (*P)[1032] = (unsigned short(*)[1032])smem;
    float rsum = 0.f;
    WAITV(4);
#pragma unroll
    for (int cf = 0; cf < 4; ++cf) {
        u16x4 pb;
#pragma unroll
        for (int r = 0; r < 4; ++r) {
            float p = __expf(acc[cf][r] * scale - rmax) * (wreg[cf][r] + 1e-10f);
            rsum += p;
            pb[r] = f2bf(p);
        }
        *(u16x4*)&P[li][cf * 128 + wv * 16 + g * 4] = pb;
    }
    WAITV(0);
#pragma unroll
    for (int cf = 4; cf < 8; ++cf) {
        u16x4 pb;
#pragma unroll
        for (int r = 0; r < 4; ++r) {
            float p = __expf(acc[cf][r] * scale - rmax) * (wreg[cf][r] + 1e-10f);
            rsum += p;
            pb[r] = f2bf(p);
        }
        *(u16x4*)&P[li][cf * 128 + wv * 16 + g * 4] = pb;
    }
    rsum += __shfl_xor(rsum, 16, 64);
    rsum += __shfl_xor(rsum, 32, 64);
    if (lane < 16) red_sum[wv][lane] = rsum;
    __syncthreads();

    const int kh = wv >> 2, p4 = wv & 3;
    f32x4 o = {};
    const unsigned short* v3s = v3 + (size_t)bh * 65536 + (size_t)(kh * 16) * 2048
                              + p4 * 512 + li * 32 + g * 8;
    short8 vA[4], vB[4];
#define VISSUE(c, vb2) do {                                                   \
        _Pragma("unroll")                                                     \
        for (int j2 = 0; j2 < 4; ++j2) gload16(vb2[j2], v3s + ((c) * 4 + j2) * 2048); \
    } while (0)
#define VCOMP(c, vb2) do {                                                    \
        __builtin_amdgcn_s_setprio(1);                                        \
        _Pragma("unroll")                                                     \
        for (int j2 = 0; j2 < 4; ++j2) {                                      \
            const int kt = kh * 16 + (c) * 4 + j2;                            \
            short8 pa = *(const short8*)&P[li][kt * 32 + koff];               \
            o = __builtin_amdgcn_mfma_f32_16x16x32_bf16(pa, vb2[j2], o, 0, 0, 0); \
        }                                                                     \
        __builtin_amdgcn_s_setprio(0);                                        \
    } while (0)
    VISSUE(0, vA);
    VISSUE(1, vB);
    WAITV(4);  VCOMP(0, vA); SBAR(); VISSUE(2, vA);
    WAITV(4);  VCOMP(1, vB); SBAR(); VISSUE(3, vB);
    WAITV(4);  VCOMP(2, vA);
    WAITV(0);  VCOMP(3, vB);
#undef VISSUE
#undef VCOMP

    if (kh == 1) po[p4][lane] = o;
    __syncthreads();
    if (kh == 0) {
        f32x4 oo = po[p4][lane];
        const int dcol = h * 64 + p4 * 16 + li;
#pragma unroll
        for (int r = 0; r < 4; ++r) {
            const int row = g * 4 + r;
            const float rs = red_sum[0][row] + red_sum[1][row] + red_sum[2][row]
                           + red_sum[3][row] + red_sum[4][row] + red_sum[5][row]
                           + red_sum[6][row] + red_sum[7][row];
            outb[(size_t)(b * NN + n0 + row) * NC + dcol] = f2bf((o[r] + oo[r]) / rs);
        }
    }

    // attn row-stores: wave wv writes rows 2wv, 2wv+1 from LDS P (bf16 -> f32), full lines
#pragma unroll
    for (int rr = 0; rr < 2; ++rr) {
        const int row = wv * 2 + rr;
        const float rs = red_sum[0][row] + red_sum[1][row] + red_sum[2][row]
                       + red_sum[3][row] + red_sum[4][row] + red_sum[5][row]
                       + red_sum[6][row] + red_sum[7][row];
        const float rv = 1.0f / rs;
        const unsigned short* prow = &P[row][0];
        float* orow = attn_out + (size_t)bh * NN * NN + (size_t)(n0 + row) * NN;
#pragma unroll
        for (int j = 0; j < 4; ++j) {
            u16x4 pv = *(const u16x4*)&prow[j * 256 + lane * 4];
            f32x4 a4;
#pragma unroll
            for (int r = 0; r < 4; ++r)
                a4[r] = __uint_as_float((unsigned)pv[r] << 16) * rv;
            __builtin_nontemporal_store(a4, (f32x4*)(orow + j * 256 + lane * 4));
        }
    }
}

// ---------- launch ----------
extern "C" void kernel_launch(void* const* d_in, const int* in_sizes, int n_in,
                              void* d_out, int out_size, void* d_ws, size_t ws_size,
                              hipStream_t stream) {
    const float* x      = (const float*)d_in[0];
    const float* mask   = (const float*)d_in[1];
    const float* weight = (const float*)d_in[2];
    const float* qkv_w  = (const float*)d_in[3];
    const float* mu_w   = (const float*)d_in[4];
    const float* mu_b   = (const float*)d_in[5];
    const float* ls_w   = (const float*)d_in[6];
    const float* ls_b   = (const float*)d_in[7];

    char* ws = (char*)d_ws;
    unsigned short* xb   = (unsigned short*)(ws + OFF_XB);
    unsigned short* wq   = (unsigned short*)(ws + OFF_WQ);
    unsigned short* wmu  = (unsigned short*)(ws + OFF_WMU);
    unsigned short* wls  = (unsigned short*)(ws + OFF_WLS);
    unsigned short* qkvb = (unsigned short*)(ws + OFF_QKVB);
    unsigned short* v3   = (unsigned short*)(ws + OFF_V3);
    unsigned short* outb = (unsigned short*)(ws + OFF_OUTB);

    float* out_mu   = (float*)d_out;
    float* out_ls   = out_mu + 3145728;
    float* out_attn = out_mu + 6291456;

    cast_all<<<5376, 256, 0, stream>>>(x, qkv_w, mu_w, ls_w, xb);

    gemm_qkv<<<dim3(TC / 128, 4096 / 128), 256, 0, stream>>>(xb, wq, qkvb);

    pack_v<<<dim3(NN / 64, NB * NH), 256, 0, stream>>>(qkvb, v3);

    attn_kernel<<<dim3(NN / 16, NB * NH), 512, 0, stream>>>(
        qkvb, v3, mask, weight, out_attn, outb);

    gemm_heads<<<dim3(NC / 128, 4096 / 128, 2), 256, 0, stream>>>(
        outb, wmu, wls, mu_b, ls_b, out_mu, out_ls);
}